// Round 3
// baseline (8665.481 us; speedup 1.0000x reference)
//
#include <hip/hip_runtime.h>
#include <stdint.h>

#define B_   128
#define T_   64
#define V_   1024
#define TS_  64
#define H_   512
#define K_   (V_ + TS_)   // 1088

// ---------------------------------------------------------------------------
// Fused time-aware GRU scan, round 15 = round 13/14 resubmit.
// r13 and r14 both died with "container failed twice" and NO timing fields
// (r0's result JSON had full timing even pre-profile) => provisioning/broker
// outage, not a kernel hang. Kernel is bounded-termination by construction:
// sticky 2^19-try worker watchdog (pays at most once), 2^17-iter heater cap,
// tag-gated poll acceptance (correct under any timing). If THIS fails the
// same way, next round reverts to r12 verbatim to discriminate kernel/infra.
//
// Changes under test (vs r12's 7.26ms):
//   (1) 3-buffer rotating issue-ahead poll (wA/wB/wC): next round always in
//       flight BEFORE waiting on the oldest -> sampling cadence ~P/3;
//       resolution ~S+P instead of ~2P.
//   (2) vmcnt decoupling: leader defers its 17-load x-prefetch until after
//       poll resolution so no poll round waits behind the 4KB prefetch in
//       the in-order vmcnt queue. Non-leaders prefetch early (they only
//       sit at the barrier).
//
// Ledger: traffic knobs dead at 64 pollers (r7/r8/r9); 256 pollers
// catastrophic (r2, r11); serial-cycle cuts work (r10 +16%); heaters (r12)
// bought ~2%. Residual ~1.8us/step vs ~1.0us ideal = poll-retry chain.
//
// Worker structure (r10): 64 WGs x 4 waves; wave q owns h[2q],h[2q+1];
// leader wave polls the packed tagged exchange (ver<<32)|(bf16<<16)|bf16,
// 4 loads/lane over 256 words, LDS broadcast + 1 barrier; DPP wave
// reduction; wave-uniform gates; 1 tagged store per wave per step.
//
// Workspace: [0,4KB) h_buf, [4KB,+64B) done word, [4224,...) heater sink.
// ---------------------------------------------------------------------------

__device__ __forceinline__ float sigmoidf_(float x) {
    return 1.0f / (1.0f + __expf(-x));
}
__device__ __forceinline__ float tanhf_(float x) {
    x = fminf(fmaxf(x, -15.0f), 15.0f);
    const float e = __expf(2.0f * x);
    return (e - 1.0f) / (e + 1.0f);
}
__device__ __forceinline__ uint32_t bf16_rn_(float f) {
    uint32_t u = __float_as_uint(f);
    u += 0x7FFFu + ((u >> 16) & 1u);   // round-to-nearest-even
    return u >> 16;
}
__device__ __forceinline__ float bf16_to_f32_(uint32_t b) {
    return __uint_as_float(b << 16);
}

// GCN DPP full-wave sum (r10-verified): row_shr 1/2/4/8, row_bcast 15/31,
// result in lane 63, readlane-broadcast.
template <int CTRL, int RM, int BM>
__device__ __forceinline__ float dpp_add_(float a) {
    const int x = __builtin_amdgcn_update_dpp(
        0, __float_as_int(a), CTRL, RM, BM, true);
    return a + __int_as_float(x);
}
__device__ __forceinline__ float wave_sum_(float a) {
    a = dpp_add_<0x111, 0xF, 0xF>(a);
    a = dpp_add_<0x112, 0xF, 0xF>(a);
    a = dpp_add_<0x114, 0xF, 0xE>(a);
    a = dpp_add_<0x118, 0xF, 0xC>(a);
    a = dpp_add_<0x142, 0xA, 0xF>(a);
    a = dpp_add_<0x143, 0xC, 0xF>(a);
    return __int_as_float(__builtin_amdgcn_readlane(__float_as_int(a), 63));
}

// issue one poll round (4 x 8B agent-relaxed loads) into dst[0..3]
#define POLL_ISSUE(dst)                                                      \
    _Pragma("unroll")                                                        \
    for (int u = 0; u < 4; ++u)                                              \
        dst[u] = __hip_atomic_load(&src[lane + 64 * u], __ATOMIC_RELAXED,    \
                                   __HIP_MEMORY_SCOPE_AGENT);

// tag-check one round (forces the s_waitcnt for that round only; younger
// in-flight rounds keep flying thanks to in-order vmcnt accounting)
#define POLL_CHECK(arr, okvar)                                               \
    okvar = true;                                                            \
    _Pragma("unroll")                                                        \
    for (int u = 0; u < 4; ++u)                                              \
        okvar = okvar && ((uint32_t)(arr[u] >> 32) == ver);

__global__ __launch_bounds__(256, 1) void gru_fused(
    const float* __restrict__ visit_emb, const float* __restrict__ intervals,
    const float* __restrict__ W_time, const float* __restrict__ b_time,
    const float* __restrict__ W_ih, const float* __restrict__ W_hh,
    const float* __restrict__ b_ih, const float* __restrict__ b_hh,
    const int* __restrict__ lens,
    uint64_t* h_buf /* [2 slot][256] tagged packed */,
    float* __restrict__ out)
{
    uint32_t* done_w = (uint32_t*)((char*)h_buf + 4096);

    // =================== HEATER BLOCKS (blockIdx >= 64) ==================
    if (blockIdx.x >= 64) {
        float a0 = (float)(blockIdx.x * 256 + threadIdx.x) * 1e-6f + 1.01f;
        float a1 = a0 + 0.1f, a2 = a0 + 0.2f, a3 = a0 + 0.3f;
        const float c = 1.0000001f, d = 1e-7f;
        // bounded spin: ~512 wave-cycles/iter * 2^17 iters ~ 28ms at 2.4GHz
        for (uint32_t it = 0; it < (1u << 17); ++it) {
            #pragma unroll
            for (int i = 0; i < 64; ++i) {     // 4 indep chains -> full issue
                a0 = fmaf(a0, c, d);
                a1 = fmaf(a1, c, d);
                a2 = fmaf(a2, c, d);
                a3 = fmaf(a3, c, d);
            }
            const uint32_t f = __hip_atomic_load(done_w, __ATOMIC_RELAXED,
                                                 __HIP_MEMORY_SCOPE_AGENT);
            if (f == 1u) break;
        }
        const float s = a0 + a1 + a2 + a3;
        if (s == 1234.56789f && threadIdx.x == 0)   // defeat DCE; never true
            ((float*)((char*)h_buf + 4224))[blockIdx.x] = s;
        return;
    }

    // =================== WORKER BLOCKS ===================================
    const int lane = threadIdx.x & 63;
    const int wave = threadIdx.x >> 6;        // 0..3
    const int q    = blockIdx.x * 4 + wave;   // 0..255 global wave id
    const int j0   = q * 2;
    const int j1   = j0 + 1;

    __shared__ float2 hs2[256];               // unpacked h pairs (fp32)
    float* hs = (float*)hs2;                  // alias: hs[512]

    float wr0[8], wr1[8], wz0[8], wz1[8], wn0[8], wn1[8];
    #pragma unroll
    for (int u = 0; u < 8; ++u) {
        const int k = lane + 64 * u;
        wr0[u] = W_hh[(size_t)j0 * H_ + k];
        wr1[u] = W_hh[(size_t)j1 * H_ + k];
        wz0[u] = W_hh[(size_t)(H_ + j0) * H_ + k];
        wz1[u] = W_hh[(size_t)(H_ + j1) * H_ + k];
        wn0[u] = W_hh[(size_t)(2 * H_ + j0) * H_ + k];
        wn1[u] = W_hh[(size_t)(2 * H_ + j1) * H_ + k];
    }
    float ir0[17], ir1[17], iz0[17], iz1[17], in0[17], in1[17];
    #pragma unroll
    for (int u = 0; u < 16; ++u) {
        const int k = lane + 64 * u;
        ir0[u] = W_ih[(size_t)j0 * K_ + k];
        ir1[u] = W_ih[(size_t)j1 * K_ + k];
        iz0[u] = W_ih[(size_t)(H_ + j0) * K_ + k];
        iz1[u] = W_ih[(size_t)(H_ + j1) * K_ + k];
        in0[u] = W_ih[(size_t)(2 * H_ + j0) * K_ + k];
        in1[u] = W_ih[(size_t)(2 * H_ + j1) * K_ + k];
    }
    ir0[16] = W_ih[(size_t)j0 * K_ + V_ + lane];
    ir1[16] = W_ih[(size_t)j1 * K_ + V_ + lane];
    iz0[16] = W_ih[(size_t)(H_ + j0) * K_ + V_ + lane];
    iz1[16] = W_ih[(size_t)(H_ + j1) * K_ + V_ + lane];
    in0[16] = W_ih[(size_t)(2 * H_ + j0) * K_ + V_ + lane];
    in1[16] = W_ih[(size_t)(2 * H_ + j1) * K_ + V_ + lane];

    const float wt = W_time[lane];
    const float bt = b_time[lane];

    const float bir0 = b_ih[j0],          bir1 = b_ih[j1];
    const float biz0 = b_ih[H_ + j0],     biz1 = b_ih[H_ + j1];
    const float bin0 = b_ih[2 * H_ + j0], bin1 = b_ih[2 * H_ + j1];
    const float bhr0 = b_hh[j0],          bhr1 = b_hh[j1];
    const float bhz0 = b_hh[H_ + j0],     bhz1 = b_hh[H_ + j1];
    const float bhn0 = b_hh[2 * H_ + j0], bhn1 = b_hh[2 * H_ + j1];

    float hj0 = 0.0f, hj1 = 0.0f;             // wave-uniform state
    uint32_t ver  = 1;    // ver 1 == initial zero state, lives in slot 1
    uint32_t dead = 0;    // leader watchdog state (wave-uniform)

    if (lane == 0)
        __hip_atomic_store(&h_buf[(ver & 1) * 256 + q], (uint64_t)ver << 32,
                           __ATOMIC_RELAXED, __HIP_MEMORY_SCOPE_AGENT);

    float xv[16];
    float iv = 0.0f;

    for (int b = 0; b < B_; ++b) {
        const int L = lens[b];
        if (L > 0) {
            iv = intervals[b * T_];
            const float* vrow = visit_emb + (size_t)(b * T_) * V_;
            #pragma unroll
            for (int u = 0; u < 16; ++u) xv[u] = vrow[lane + 64 * u];
        }
        for (int t = 0; t < L; ++t) {
            const uint64_t* src = h_buf + (ver & 1) * 256;
            uint64_t wA[4], wB[4];

            // ---- leader: round A in flight before anything else ---------
            if (wave == 0) { POLL_ISSUE(wA) }

            // ---- x-side dots (h-independent; overlap the sweep) ---------
            const float xt = fmaf(iv, wt, bt);
            float ar0 = ir0[16] * xt, ar1 = ir1[16] * xt;
            float az0 = iz0[16] * xt, az1 = iz1[16] * xt;
            float xn0 = in0[16] * xt, xn1 = in1[16] * xt;
            #pragma unroll
            for (int u = 0; u < 16; ++u) {
                ar0 = fmaf(ir0[u], xv[u], ar0);
                ar1 = fmaf(ir1[u], xv[u], ar1);
                az0 = fmaf(iz0[u], xv[u], az0);
                az1 = fmaf(iz1[u], xv[u], az1);
                xn0 = fmaf(in0[u], xv[u], xn0);
                xn1 = fmaf(in1[u], xv[u], xn1);
            }

            // ---- leader: round B in flight BEFORE any prefetch loads ----
            if (wave == 0) { POLL_ISSUE(wB) }

            // ---- non-leaders: prefetch next x row now (they only hit the
            //      barrier next; their vmcnt never gates the poll) --------
            if (wave != 0 && t + 1 < L) {
                iv = intervals[b * T_ + t + 1];
                const float* vrow = visit_emb + (size_t)(b * T_ + t + 1) * V_;
                #pragma unroll
                for (int u = 0; u < 16; ++u) xv[u] = vrow[lane + 64 * u];
            }

            // ---- leader: rotating issue-ahead poll; winner ends in wA ---
            if (wave == 0) {
                if (!dead) {
                    bool ok;
                    POLL_CHECK(wA, ok)
                    if (!__all(ok)) {
                        uint64_t wC[4];
                        POLL_ISSUE(wC)            // 3rd round in flight
                        uint32_t tries = 0;
                        int rot = 0;              // which buffer to check next
                        for (;;) {
                            if (++tries > (1u << 19)) { dead = 1; break; }
                            if (rot == 0) {
                                POLL_ISSUE(wA)    // reissue stale A first
                                POLL_CHECK(wB, ok)
                                if (__all(ok)) {
                                    #pragma unroll
                                    for (int u = 0; u < 4; ++u) wA[u] = wB[u];
                                    break;
                                }
                                rot = 1;
                            } else if (rot == 1) {
                                POLL_ISSUE(wB)
                                POLL_CHECK(wC, ok)
                                if (__all(ok)) {
                                    #pragma unroll
                                    for (int u = 0; u < 4; ++u) wA[u] = wC[u];
                                    break;
                                }
                                rot = 2;
                            } else {
                                POLL_ISSUE(wC)
                                POLL_CHECK(wA, ok)
                                if (__all(ok)) break;
                                rot = 0;
                            }
                        }
                    }
                }
                // unpack winner into LDS
                #pragma unroll
                for (int u = 0; u < 4; ++u) {
                    const uint32_t d = (uint32_t)wA[u];
                    hs2[lane + 64 * u] =
                        make_float2(bf16_to_f32_(d & 0xFFFFu),
                                    bf16_to_f32_(d >> 16));
                }
                // leader's deferred prefetch: issued only after the poll is
                // resolved, so it can never sit ahead of a poll round in the
                // vmcnt queue. It flies across the barrier and the next
                // step's x-dots give it ~300cy of slack (L2-resident row).
                if (t + 1 < L) {
                    iv = intervals[b * T_ + t + 1];
                    const float* vrow =
                        visit_emb + (size_t)(b * T_ + t + 1) * V_;
                    #pragma unroll
                    for (int u = 0; u < 16; ++u) xv[u] = vrow[lane + 64 * u];
                }
            }
            __syncthreads();

            float h[8];
            #pragma unroll
            for (int u = 0; u < 8; ++u) h[u] = hs[lane + 64 * u];

            // ---- h-side dots; r/z merged with x-side, n kept split ------
            float hn0 = 0.0f, hn1 = 0.0f;
            #pragma unroll
            for (int u = 0; u < 8; ++u) {
                ar0 = fmaf(wr0[u], h[u], ar0);
                ar1 = fmaf(wr1[u], h[u], ar1);
                az0 = fmaf(wz0[u], h[u], az0);
                az1 = fmaf(wz1[u], h[u], az1);
                hn0 = fmaf(wn0[u], h[u], hn0);
                hn1 = fmaf(wn1[u], h[u], hn1);
            }

            // ---- 8 pipelined DPP wave sums (VALU, no LDS rounds) --------
            const float sr0 = wave_sum_(ar0), sr1 = wave_sum_(ar1);
            const float sz0 = wave_sum_(az0), sz1 = wave_sum_(az1);
            const float sx0 = wave_sum_(xn0), sx1 = wave_sum_(xn1);
            const float sh0 = wave_sum_(hn0), sh1 = wave_sum_(hn1);

            // ---- gates & recurrence (wave-uniform) ----------------------
            const float r0 = sigmoidf_(sr0 + bir0 + bhr0);
            const float r1 = sigmoidf_(sr1 + bir1 + bhr1);
            const float z0 = sigmoidf_(sz0 + biz0 + bhz0);
            const float z1 = sigmoidf_(sz1 + biz1 + bhz1);
            const float n0 = tanhf_(sx0 + bin0 + r0 * (sh0 + bhn0));
            const float n1 = tanhf_(sx1 + bin1 + r1 * (sh1 + bhn1));
            hj0 = (1.0f - z0) * n0 + z0 * hj0;
            hj1 = (1.0f - z1) * n1 + z1 * hj1;

            // ---- publish ONE tagged packed word per wave ----------------
            ++ver;
            if (lane == 0) {
                const uint32_t packed =
                    bf16_rn_(hj0) | (bf16_rn_(hj1) << 16);
                __hip_atomic_store(&h_buf[(ver & 1) * 256 + q],
                    ((uint64_t)ver << 32) | (uint64_t)packed,
                    __ATOMIC_RELAXED, __HIP_MEMORY_SCOPE_AGENT);
            }
        }
        // out[b] = h after sample b's (possibly empty) segment
        if (lane < 2) out[b * H_ + j0 + lane] = (lane == 0) ? hj0 : hj1;
    }

    // last wave signals the heaters to stop (everyone else is within +-1
    // step of q==255, so heat never extends the dispatch)
    if (q == 255 && lane == 0)
        __hip_atomic_store(done_w, 1u, __ATOMIC_RELAXED,
                           __HIP_MEMORY_SCOPE_AGENT);
}

// ---------------------------------------------------------------------------
extern "C" void kernel_launch(void* const* d_in, const int* in_sizes, int n_in,
                              void* d_out, int out_size, void* d_ws, size_t ws_size,
                              hipStream_t stream)
{
    const float* visit_emb = (const float*)d_in[0];
    const float* intervals = (const float*)d_in[1];
    const float* W_time    = (const float*)d_in[2];
    const float* b_time    = (const float*)d_in[3];
    const float* W_ih      = (const float*)d_in[4];
    const float* W_hh      = (const float*)d_in[5];
    const float* b_ih      = (const float*)d_in[6];
    const float* b_hh      = (const float*)d_in[7];
    const int*   lens      = (const int*)d_in[8];
    float*       out       = (float*)d_out;

    // workspace: [0,4KB) packed tagged h exchange; [4KB) done; [4224) sink
    uint64_t* h_buf = (uint64_t*)d_ws;

    gru_fused<<<256, 256, 0, stream>>>(visit_emb, intervals, W_time, b_time,
                                       W_ih, W_hh, b_ih, b_hh, lens, h_buf, out);
}